// Round 23
// baseline (784.418 us; speedup 1.0000x reference)
//
#include <hip/hip_runtime.h>
#include <stdio.h>

#define NBP   8192
#define MTOT  8192
#define CIN   64
#define CO    128

#define EPR(...) do { fprintf(stderr, __VA_ARGS__); fflush(stderr); } while (0)

typedef short short8 __attribute__((ext_vector_type(8)));
typedef float floatx4 __attribute__((ext_vector_type(4)));
typedef unsigned short ushort;

__device__ __forceinline__ ushort f2b(float f)
{
    union { unsigned int i; float f; } x; x.f = f;
    return (ushort)((x.i + 0x7fffu + ((x.i >> 16) & 1u)) >> 16);
}
__device__ __forceinline__ float b2f(ushort u)
{
    union { unsigned int i; float f; } x; x.i = ((unsigned int)u) << 16;
    return x.f;
}

// ---------------------------------------------------------------------------
// Zero stats; write output 0 = new_xyz (f32 copy).
// ---------------------------------------------------------------------------
__global__ void __launch_bounds__(256, 1) StackSAModuleMSG_85761906966880_kernel(
    const float* __restrict__ nxyz, float* __restrict__ out, float* __restrict__ stats)
{
    int i = blockIdx.x * 256 + threadIdx.x;
    if (i < 1024) stats[i] = 0.f;
    if (i < MTOT*3) out[i] = nxyz[i];
}

// ---------------------------------------------------------------------------
// Split W1 weights (both scales) into bf16 hi/lo once.
// ---------------------------------------------------------------------------
__global__ void __launch_bounds__(256, 1) sa_wprep(
    const float* __restrict__ wA, const float* __restrict__ wB,
    ushort* __restrict__ whA, ushort* __restrict__ wlA,
    ushort* __restrict__ whB, ushort* __restrict__ wlB)
{
    int i = blockIdx.x * 256 + threadIdx.x;
    if (i >= 128*128) return;
    float a = wA[i];
    ushort h = f2b(a);
    whA[i] = h; wlA[i] = f2b(a - b2f(h));
    float b = wB[i];
    ushort h2 = f2b(b);
    whB[i] = h2; wlB[i] = f2b(b - b2f(h2));
}

// ---------------------------------------------------------------------------
// Ball query, both scales: one wave per query; f64 d2 (matches np gold).
// ---------------------------------------------------------------------------
__global__ void __launch_bounds__(64, 1) sa_ballq(
    const float* __restrict__ xyz, const float* __restrict__ new_xyz,
    int* __restrict__ idx0, int* __restrict__ idx1,
    int* __restrict__ empty0, int* __restrict__ empty1)
{
    const double r2a = 0.2 * 0.2;
    const double r2b = 0.4 * 0.4;
    int m    = blockIdx.x;
    int lane = threadIdx.x;
    int b    = m >> 11;
    int base = b * NBP;

    double nx = (double)new_xyz[3*m+0];
    double ny = (double)new_xyz[3*m+1];
    double nz = (double)new_xyz[3*m+2];
    double nn = nx*nx + ny*ny + nz*nz;

    int cnt0 = 0, cnt1 = 0;
    int first0 = base, first1 = base;
    unsigned long long lt = (1ull << lane) - 1ull;

    for (int j = 0; j < NBP; j += 64) {
        int gi = base + j + lane;
        double px = (double)xyz[3*gi+0];
        double py = (double)xyz[3*gi+1];
        double pz = (double)xyz[3*gi+2];
        double pp = px*px + py*py + pz*pz;
        double dt = nx*px + ny*py + nz*pz;
        double d2 = nn + pp - 2.0*dt;
        bool in0 = d2 < r2a;
        bool in1 = d2 < r2b;
        unsigned long long m0 = __ballot(in0);
        unsigned long long m1 = __ballot(in1);
        if (in0) {
            int p = cnt0 + __popcll(m0 & lt);
            if (p < 16) idx0[m*16 + p] = gi;
        }
        if (in1) {
            int p = cnt1 + __popcll(m1 & lt);
            if (p < 32) idx1[m*32 + p] = gi;
        }
        if (cnt0 == 0 && m0) first0 = base + j + (__ffsll((long long)m0) - 1);
        if (cnt1 == 0 && m1) first1 = base + j + (__ffsll((long long)m1) - 1);
        cnt0 += __popcll(m0);
        cnt1 += __popcll(m1);
        if (cnt0 >= 16 && cnt1 >= 32) break;
    }
    int c0 = cnt0 < 16 ? cnt0 : 16;
    int c1 = cnt1 < 32 ? cnt1 : 32;
    if (lane >= c0 && lane < 16) idx0[m*16 + lane] = first0;
    if (lane >= c1 && lane < 32) idx1[m*32 + lane] = first1;
    if (lane == 0) { empty0[m] = (cnt0 == 0); empty1[m] = (cnt1 == 0); }
}

// ---------------------------------------------------------------------------
// Pass 1 (R21 proven, acc[i][3] line restored): MB=2 groups, 4 waves,
// stride-68 panels, permuted k-layout. x1 = G @ W0^T + stats1.
// ---------------------------------------------------------------------------
template<int NS>
__global__ void __launch_bounds__(256, 2) sa_pass1(
    const float* __restrict__ xyz, const float* __restrict__ feat,
    const float* __restrict__ nxyz, const int* __restrict__ idx,
    const int* __restrict__ empty, const float* __restrict__ w0,
    float* __restrict__ x1, float* __restrict__ ssum, float* __restrict__ ssq)
{
    const int ROWS = 2*NS;
    const int RH   = NS/4;
    __shared__ float gs[ROWS*68];
    __shared__ float ws[128*68];
    __shared__ float sred[8*128];
    __shared__ float qred[8*128];
    __shared__ int   lidx[64];
    int bx = blockIdx.x, t = threadIdx.x;
    int m0 = 2*bx;
    int wv = t >> 6, L = t & 63, hf = L >> 5, li = L & 31;

    if (t < ROWS) lidx[t] = idx[(long long)m0*NS + t];
    __syncthreads();
    int emp0 = empty[m0], emp1 = empty[m0+1];

    for (int e = t; e < ROWS*16; e += 256) {
        int n = e >> 4, c4 = e & 15;
        int gi = lidx[n];
        float4 v = *(const float4*)(feat + (long long)gi*CIN + 4*c4);
        int g = n / NS;
        if (g ? emp1 : emp0) { v.x = 0.f; v.y = 0.f; v.z = 0.f; v.w = 0.f; }
        *(float4*)(gs + n*68 + 4*c4) = v;
    }
    for (int e = t; e < ROWS*4; e += 256) {
        int n = e >> 2, c = e & 3;
        float v = 0.f;
        if (c < 3) {
            int g = n / NS;
            if (!(g ? emp1 : emp0)) {
                int gi = lidx[n];
                v = xyz[3*gi+c] - nxyz[3*(m0+g)+c];
            }
        }
        gs[n*68 + 64 + c] = v;
    }
    for (int e = t; e < 2144; e += 256) {
        float4 v = *(const float4*)(w0 + 4*e);
        float vv[4] = {v.x, v.y, v.z, v.w};
#pragma unroll
        for (int u = 0; u < 4; u++) {
            int f = 4*e + u;
            int o = f / 67, c = f - o*67;
            int kd = (c >= 3) ? (c - 3) : (64 + c);
            ws[o*68 + kd] = vv[u];
        }
    }
    if (t < 128) ws[t*68 + 67] = 0.f;
    __syncthreads();

    float acc[RH][4];
#pragma unroll
    for (int i = 0; i < RH; i++)
        { acc[i][0]=0.f; acc[i][1]=0.f; acc[i][2]=0.f; acc[i][3]=0.f; }
    int c0 = li, c1 = li+32, c2 = li+64, c3 = li+96;
    int r0 = wv*(NS/2) + hf*RH;

    for (int q = 0; q < 17; q++) {
        int k = 4*q;
        float4 w0v = *(const float4*)(ws + c0*68 + k);
        float4 w1v = *(const float4*)(ws + c1*68 + k);
        float4 w2v = *(const float4*)(ws + c2*68 + k);
        float4 w3v = *(const float4*)(ws + c3*68 + k);
#pragma unroll
        for (int i = 0; i < RH; i++) {
            float4 g = *(const float4*)(gs + (r0+i)*68 + k);
            acc[i][0]=fmaf(g.x,w0v.x,acc[i][0]); acc[i][0]=fmaf(g.y,w0v.y,acc[i][0]);
            acc[i][0]=fmaf(g.z,w0v.z,acc[i][0]); acc[i][0]=fmaf(g.w,w0v.w,acc[i][0]);
            acc[i][1]=fmaf(g.x,w1v.x,acc[i][1]); acc[i][1]=fmaf(g.y,w1v.y,acc[i][1]);
            acc[i][1]=fmaf(g.z,w1v.z,acc[i][1]); acc[i][1]=fmaf(g.w,w1v.w,acc[i][1]);
            acc[i][2]=fmaf(g.x,w2v.x,acc[i][2]); acc[i][2]=fmaf(g.y,w2v.y,acc[i][2]);
            acc[i][2]=fmaf(g.z,w2v.z,acc[i][2]); acc[i][2]=fmaf(g.w,w2v.w,acc[i][2]);
            acc[i][3]=fmaf(g.x,w3v.x,acc[i][3]); acc[i][3]=fmaf(g.y,w3v.y,acc[i][3]);
            acc[i][3]=fmaf(g.z,w3v.z,acc[i][3]); acc[i][3]=fmaf(g.w,w3v.w,acc[i][3]);
        }
    }

    long long gbase = (long long)m0*NS*CO;
    float s[4] = {0,0,0,0}, qv[4] = {0,0,0,0};
#pragma unroll
    for (int i = 0; i < RH; i++) {
        long long rb = gbase + (long long)(r0+i)*CO;
        x1[rb+c0]=acc[i][0]; x1[rb+c1]=acc[i][1];
        x1[rb+c2]=acc[i][2]; x1[rb+c3]=acc[i][3];
#pragma unroll
        for (int j = 0; j < 4; j++) {
            s[j] += acc[i][j]; qv[j] = fmaf(acc[i][j], acc[i][j], qv[j]);
        }
    }
    int p = wv*2 + hf;
    sred[p*128+c0]=s[0]; sred[p*128+c1]=s[1]; sred[p*128+c2]=s[2]; sred[p*128+c3]=s[3];
    qred[p*128+c0]=qv[0]; qred[p*128+c1]=qv[1]; qred[p*128+c2]=qv[2]; qred[p*128+c3]=qv[3];
    __syncthreads();
    if (t < 128) {
        float ss = 0.f, qq = 0.f;
#pragma unroll
        for (int r = 0; r < 8; r++) { ss += sred[r*128+t]; qq += qred[r*128+t]; }
        atomicAdd(&ssum[t], ss); atomicAdd(&ssq[t], qq);
    }
}

// ---------------------------------------------------------------------------
// Pass 2 (MFMA, split-bf16): one query group per block, 4 waves.
// h = relu(BN1(x1)) split to bf16 hi/lo LDS panels (stride 136 ushorts).
// Wave wv owns 32 channels; MT m-tiles x 2 n-tiles, K=128 in 4 steps.
// Verified gfx950 layouts: A[m=lane&15][k=quad*8+j], B[k=quad*8+j][n=lane&15],
// C/D col=lane&15 (channel), row=quad*4+reg (sample).
// ---------------------------------------------------------------------------
template<int NS>
__global__ void __launch_bounds__(256, 2) sa_pass2m(
    const float* __restrict__ x1, const ushort* __restrict__ wh,
    const ushort* __restrict__ wl,
    const float* __restrict__ g0, const float* __restrict__ b0,
    const float* __restrict__ s1sum, const float* __restrict__ s1sq,
    float* __restrict__ s2sum, float* __restrict__ s2sq,
    float* __restrict__ mxo, float* __restrict__ mno, float invN)
{
    const int MT = NS/16;
    __shared__ ushort ah[NS*136];
    __shared__ ushort al[NS*136];
    __shared__ float kv[128], sv[128];
    int m = blockIdx.x, t = threadIdx.x;
    int wv = t >> 6, lane = t & 63, l16 = lane & 15, qo = lane >> 4;

    if (t < 128) {
        float mean = s1sum[t] * invN;
        float var  = s1sq[t] * invN - mean * mean;
        float k    = rsqrtf(var + 1e-5f) * g0[t];
        kv[t] = k;
        sv[t] = b0[t] - mean * k;
    }
    __syncthreads();

    long long base = (long long)m * NS * 128;
    for (int e = t; e < NS*32; e += 256) {
        int n = e >> 5, c4 = e & 31;
        float4 v  = *(const float4*)(x1 + base + (long long)n*128 + 4*c4);
        float4 kk = *(const float4*)(kv + 4*c4);
        float4 ss = *(const float4*)(sv + 4*c4);
        float h0 = fmaxf(fmaf(v.x, kk.x, ss.x), 0.f);
        float h1 = fmaxf(fmaf(v.y, kk.y, ss.y), 0.f);
        float h2 = fmaxf(fmaf(v.z, kk.z, ss.z), 0.f);
        float h3 = fmaxf(fmaf(v.w, kk.w, ss.w), 0.f);
        int o = n*136 + 4*c4;
        ushort u0 = f2b(h0), u1 = f2b(h1), u2 = f2b(h2), u3 = f2b(h3);
        ah[o+0] = u0; ah[o+1] = u1; ah[o+2] = u2; ah[o+3] = u3;
        al[o+0] = f2b(h0 - b2f(u0));
        al[o+1] = f2b(h1 - b2f(u1));
        al[o+2] = f2b(h2 - b2f(u2));
        al[o+3] = f2b(h3 - b2f(u3));
    }
    __syncthreads();

    floatx4 acc[MT][2];
#pragma unroll
    for (int i = 0; i < MT; i++) {
        acc[i][0] = (floatx4){0.f,0.f,0.f,0.f};
        acc[i][1] = (floatx4){0.f,0.f,0.f,0.f};
    }
    int n0 = 32*wv;

    for (int ks = 0; ks < 4; ks++) {
        int kb = ks*32 + qo*8;
        short8 bh[2], bl[2];
#pragma unroll
        for (int nt = 0; nt < 2; nt++) {
            long long wo = (long long)(n0 + 16*nt + l16)*128 + kb;
            bh[nt] = *(const short8*)(wh + wo);
            bl[nt] = *(const short8*)(wl + wo);
        }
#pragma unroll
        for (int mt = 0; mt < MT; mt++) {
            int ao = (16*mt + l16)*136 + kb;
            short8 fh = *(const short8*)(ah + ao);
            short8 fl = *(const short8*)(al + ao);
#pragma unroll
            for (int nt = 0; nt < 2; nt++) {
                acc[mt][nt] = __builtin_amdgcn_mfma_f32_16x16x32_bf16(
                                  fl, bh[nt], acc[mt][nt], 0, 0, 0);
                acc[mt][nt] = __builtin_amdgcn_mfma_f32_16x16x32_bf16(
                                  fh, bl[nt], acc[mt][nt], 0, 0, 0);
                acc[mt][nt] = __builtin_amdgcn_mfma_f32_16x16x32_bf16(
                                  fh, bh[nt], acc[mt][nt], 0, 0, 0);
            }
        }
    }

    // epilogue: per-channel (col=lane&15) sums/max/min over samples
    float sum[2], sq[2], mx[2], mn[2];
#pragma unroll
    for (int nt = 0; nt < 2; nt++) {
        float s = 0.f, q = 0.f, M = -3.4e38f, N = 3.4e38f;
#pragma unroll
        for (int mt = 0; mt < MT; mt++) {
#pragma unroll
            for (int r = 0; r < 4; r++) {
                float a = acc[mt][nt][r];
                s += a; q = fmaf(a, a, q);
                M = fmaxf(M, a); N = fminf(N, a);
            }
        }
        s += __shfl_xor(s, 16); s += __shfl_xor(s, 32);
        q += __shfl_xor(q, 16); q += __shfl_xor(q, 32);
        M = fmaxf(M, __shfl_xor(M, 16)); M = fmaxf(M, __shfl_xor(M, 32));
        N = fminf(N, __shfl_xor(N, 16)); N = fminf(N, __shfl_xor(N, 32));
        sum[nt] = s; sq[nt] = q; mx[nt] = M; mn[nt] = N;
    }
    if (lane < 16) {
#pragma unroll
        for (int nt = 0; nt < 2; nt++) {
            int c = n0 + 16*nt + lane;
            atomicAdd(&s2sum[c], sum[nt]);
            atomicAdd(&s2sq[c],  sq[nt]);
            mxo[(long long)m*128 + c] = mx[nt];
            mno[(long long)m*128 + c] = mn[nt];
        }
    }
}

// ---------------------------------------------------------------------------
// Pass 3 (tiny): out = relu(k2 * (k2>=0 ? max : min) + sh2) per (m, o).
// ---------------------------------------------------------------------------
__global__ void __launch_bounds__(256, 1) sa_pass3(
    const float* __restrict__ mxo, const float* __restrict__ mno,
    const float* __restrict__ g1, const float* __restrict__ b1,
    const float* __restrict__ s2sum, const float* __restrict__ s2sq,
    float* __restrict__ outp, float invN)
{
    int i = blockIdx.x * 256 + threadIdx.x;
    if (i >= MTOT*128) return;
    int m = i >> 7, o = i & 127;
    float mean = s2sum[o] * invN;
    float var  = s2sq[o] * invN - mean * mean;
    float k    = rsqrtf(var + 1e-5f) * g1[o];
    float sh   = b1[o] - mean * k;
    float v    = (k >= 0.f) ? mxo[i] : mno[i];
    float r    = fmaf(v, k, sh);
    outp[(long long)m*256 + o] = r > 0.f ? r : 0.f;
}

// ---------------------------------------------------------------------------
extern "C" void kernel_launch(void* const* d_in, const int* in_sizes, int n_in,
                              void* d_out, int out_size, void* d_ws, size_t ws_size,
                              hipStream_t stream)
{
    const float* xyz  = (const float*)d_in[0];
    const float* feat = (const float*)d_in[1];
    const float* nxyz = (const float*)d_in[2];
    const float* w00 = (const float*)d_in[5];
    const float* g00 = (const float*)d_in[6];
    const float* b00 = (const float*)d_in[7];
    const float* w01 = (const float*)d_in[8];
    const float* g01 = (const float*)d_in[9];
    const float* b01 = (const float*)d_in[10];
    const float* w10 = (const float*)d_in[11];
    const float* g10 = (const float*)d_in[12];
    const float* b10 = (const float*)d_in[13];
    const float* w11 = (const float*)d_in[14];
    const float* g11 = (const float*)d_in[15];
    const float* b11 = (const float*)d_in[16];
    float* out = (float*)d_out;

    char*  wsb    = (char*)d_ws;
    float* stats  = (float*)(wsb);
    int*   idx0   = (int*)(wsb + 4096);
    int*   idx1   = (int*)(wsb + 4096 + 524288);
    int*   empty0 = (int*)(wsb + 4096 + 524288 + 1048576);
    int*   empty1 = (int*)(wsb + 4096 + 524288 + 1048576 + 32768);
    float* x      = (float*)(wsb + 4096 + 524288 + 1048576 + 65536);
    float* mx0    = (float*)(wsb + 150000000);
    float* mn0    = (float*)(wsb + 155000000);
    float* mx1    = (float*)(wsb + 160000000);
    float* mn1    = (float*)(wsb + 165000000);
    ushort* whA   = (ushort*)(wsb + 170000000);   // split of w01 (scale 0)
    ushort* wlA   = (ushort*)(wsb + 171000000);
    ushort* whB   = (ushort*)(wsb + 172000000);   // split of w11 (scale 1)
    ushort* wlB   = (ushort*)(wsb + 173000000);

    StackSAModuleMSG_85761906966880_kernel<<<96, 256, 0, stream>>>(nxyz, out, stats);
    sa_wprep<<<64, 256, 0, stream>>>(w01, w11, whA, wlA, whB, wlB);
    sa_ballq<<<MTOT, 64, 0, stream>>>(xyz, nxyz, idx0, idx1, empty0, empty1);

    float* fout = out + MTOT*3;
    const float invN0 = 1.0f / (float)(MTOT*16);
    const float invN1 = 1.0f / (float)(MTOT*32);
    const int P3B = (MTOT*128 + 255) / 256;
    const int GB  = MTOT/2;

    // scale 0 (r=0.2, ns=16)
    sa_pass1<16><<<GB, 256, 0, stream>>>(xyz, feat, nxyz, idx0, empty0, w00,
                                         x, stats + 0, stats + 128);
    sa_pass2m<16><<<MTOT, 256, 0, stream>>>(x, whA, wlA, g00, b00,
                                            stats + 0, stats + 128,
                                            stats + 256, stats + 384, mx0, mn0, invN0);
    sa_pass3<<<P3B, 256, 0, stream>>>(mx0, mn0, g01, b01, stats + 256, stats + 384,
                                      fout, invN0);
    // scale 1 (r=0.4, ns=32)
    sa_pass1<32><<<GB, 256, 0, stream>>>(xyz, feat, nxyz, idx1, empty1, w10,
                                         x, stats + 512, stats + 640);
    sa_pass2m<32><<<MTOT, 256, 0, stream>>>(x, whB, wlB, g10, b10,
                                            stats + 512, stats + 640,
                                            stats + 768, stats + 896, mx1, mn1, invN1);
    sa_pass3<<<P3B, 256, 0, stream>>>(mx1, mn1, g11, b11, stats + 768, stats + 896,
                                      fout + 128, invN1);

    hipError_t e = hipGetLastError();
    if (e != hipSuccess) EPR("[KL] enqueue err=%d (%s)\n", (int)e, hipGetErrorString(e));
}

// Round 24
// 365.733 us; speedup vs baseline: 2.1448x; 2.1448x over previous
//
#include <hip/hip_runtime.h>
#include <stdio.h>

#define NBP   8192
#define MTOT  8192
#define CIN   64
#define CO    128

#define EPR(...) do { fprintf(stderr, __VA_ARGS__); fflush(stderr); } while (0)

typedef short short8 __attribute__((ext_vector_type(8)));
typedef float floatx4 __attribute__((ext_vector_type(4)));
typedef unsigned short ushort;

__device__ __forceinline__ ushort f2b(float f)
{
    union { unsigned int i; float f; } x; x.f = f;
    return (ushort)((x.i + 0x7fffu + ((x.i >> 16) & 1u)) >> 16);
}
__device__ __forceinline__ float b2f(ushort u)
{
    union { unsigned int i; float f; } x; x.i = ((unsigned int)u) << 16;
    return x.f;
}

// ---------------------------------------------------------------------------
// Zero stats; write output 0 = new_xyz (f32 copy).
// ---------------------------------------------------------------------------
__global__ void __launch_bounds__(256, 1) StackSAModuleMSG_85761906966880_kernel(
    const float* __restrict__ nxyz, float* __restrict__ out, float* __restrict__ stats)
{
    int i = blockIdx.x * 256 + threadIdx.x;
    if (i < 1024) stats[i] = 0.f;
    if (i < MTOT*3) out[i] = nxyz[i];
}

// ---------------------------------------------------------------------------
// Split W1 weights (both scales) into bf16 hi/lo once.
// ---------------------------------------------------------------------------
__global__ void __launch_bounds__(256, 1) sa_wprep(
    const float* __restrict__ wA, const float* __restrict__ wB,
    ushort* __restrict__ whA, ushort* __restrict__ wlA,
    ushort* __restrict__ whB, ushort* __restrict__ wlB)
{
    int i = blockIdx.x * 256 + threadIdx.x;
    if (i >= 128*128) return;
    float a = wA[i];
    ushort h = f2b(a);
    whA[i] = h; wlA[i] = f2b(a - b2f(h));
    float b = wB[i];
    ushort h2 = f2b(b);
    whB[i] = h2; wlB[i] = f2b(b - b2f(h2));
}

// ---------------------------------------------------------------------------
// Reduce per-block partial stats rows (256 floats each) into stats dst.
// Block b sums slot b across nb rows.
// ---------------------------------------------------------------------------
__global__ void __launch_bounds__(256, 1) sa_reduce(
    const float* __restrict__ part, float* __restrict__ dst, int nb)
{
    __shared__ float red[256];
    int b = blockIdx.x, t = threadIdx.x;
    float s = 0.f;
    for (int i = t; i < nb; i += 256) s += part[(long long)i*256 + b];
    red[t] = s;
    __syncthreads();
    for (int off = 128; off > 0; off >>= 1) {
        if (t < off) red[t] += red[t + off];
        __syncthreads();
    }
    if (t == 0) dst[b] = red[0];
}

// ---------------------------------------------------------------------------
// Ball query, both scales: one wave per query; f64 d2 (matches np gold).
// ---------------------------------------------------------------------------
__global__ void __launch_bounds__(64, 1) sa_ballq(
    const float* __restrict__ xyz, const float* __restrict__ new_xyz,
    int* __restrict__ idx0, int* __restrict__ idx1,
    int* __restrict__ empty0, int* __restrict__ empty1)
{
    const double r2a = 0.2 * 0.2;
    const double r2b = 0.4 * 0.4;
    int m    = blockIdx.x;
    int lane = threadIdx.x;
    int b    = m >> 11;
    int base = b * NBP;

    double nx = (double)new_xyz[3*m+0];
    double ny = (double)new_xyz[3*m+1];
    double nz = (double)new_xyz[3*m+2];
    double nn = nx*nx + ny*ny + nz*nz;

    int cnt0 = 0, cnt1 = 0;
    int first0 = base, first1 = base;
    unsigned long long lt = (1ull << lane) - 1ull;

    for (int j = 0; j < NBP; j += 64) {
        int gi = base + j + lane;
        double px = (double)xyz[3*gi+0];
        double py = (double)xyz[3*gi+1];
        double pz = (double)xyz[3*gi+2];
        double pp = px*px + py*py + pz*pz;
        double dt = nx*px + ny*py + nz*pz;
        double d2 = nn + pp - 2.0*dt;
        bool in0 = d2 < r2a;
        bool in1 = d2 < r2b;
        unsigned long long m0 = __ballot(in0);
        unsigned long long m1 = __ballot(in1);
        if (in0) {
            int p = cnt0 + __popcll(m0 & lt);
            if (p < 16) idx0[m*16 + p] = gi;
        }
        if (in1) {
            int p = cnt1 + __popcll(m1 & lt);
            if (p < 32) idx1[m*32 + p] = gi;
        }
        if (cnt0 == 0 && m0) first0 = base + j + (__ffsll((long long)m0) - 1);
        if (cnt1 == 0 && m1) first1 = base + j + (__ffsll((long long)m1) - 1);
        cnt0 += __popcll(m0);
        cnt1 += __popcll(m1);
        if (cnt0 >= 16 && cnt1 >= 32) break;
    }
    int c0 = cnt0 < 16 ? cnt0 : 16;
    int c1 = cnt1 < 32 ? cnt1 : 32;
    if (lane >= c0 && lane < 16) idx0[m*16 + lane] = first0;
    if (lane >= c1 && lane < 32) idx1[m*32 + lane] = first1;
    if (lane == 0) { empty0[m] = (cnt0 == 0); empty1[m] = (cnt1 == 0); }
}

// ---------------------------------------------------------------------------
// Pass 1 (R21 proven geometry): MB=2 groups, 4 waves, stride-68 panels,
// permuted k-layout. x1 = G @ W0^T; per-block partial stats (no atomics).
// ---------------------------------------------------------------------------
template<int NS>
__global__ void __launch_bounds__(256, 2) sa_pass1(
    const float* __restrict__ xyz, const float* __restrict__ feat,
    const float* __restrict__ nxyz, const int* __restrict__ idx,
    const int* __restrict__ empty, const float* __restrict__ w0,
    float* __restrict__ x1, float* __restrict__ part)
{
    const int ROWS = 2*NS;
    const int RH   = NS/4;
    __shared__ float gs[ROWS*68];
    __shared__ float ws[128*68];
    __shared__ float sred[8*128];
    __shared__ float qred[8*128];
    __shared__ int   lidx[64];
    int bx = blockIdx.x, t = threadIdx.x;
    int m0 = 2*bx;
    int wv = t >> 6, L = t & 63, hf = L >> 5, li = L & 31;

    if (t < ROWS) lidx[t] = idx[(long long)m0*NS + t];
    __syncthreads();
    int emp0 = empty[m0], emp1 = empty[m0+1];

    for (int e = t; e < ROWS*16; e += 256) {
        int n = e >> 4, c4 = e & 15;
        int gi = lidx[n];
        float4 v = *(const float4*)(feat + (long long)gi*CIN + 4*c4);
        int g = n / NS;
        if (g ? emp1 : emp0) { v.x = 0.f; v.y = 0.f; v.z = 0.f; v.w = 0.f; }
        *(float4*)(gs + n*68 + 4*c4) = v;
    }
    for (int e = t; e < ROWS*4; e += 256) {
        int n = e >> 2, c = e & 3;
        float v = 0.f;
        if (c < 3) {
            int g = n / NS;
            if (!(g ? emp1 : emp0)) {
                int gi = lidx[n];
                v = xyz[3*gi+c] - nxyz[3*(m0+g)+c];
            }
        }
        gs[n*68 + 64 + c] = v;
    }
    for (int e = t; e < 2144; e += 256) {
        float4 v = *(const float4*)(w0 + 4*e);
        float vv[4] = {v.x, v.y, v.z, v.w};
#pragma unroll
        for (int u = 0; u < 4; u++) {
            int f = 4*e + u;
            int o = f / 67, c = f - o*67;
            int kd = (c >= 3) ? (c - 3) : (64 + c);
            ws[o*68 + kd] = vv[u];
        }
    }
    if (t < 128) ws[t*68 + 67] = 0.f;
    __syncthreads();

    float acc[RH][4];
#pragma unroll
    for (int i = 0; i < RH; i++)
        { acc[i][0]=0.f; acc[i][1]=0.f; acc[i][2]=0.f; acc[i][3]=0.f; }
    int c0 = li, c1 = li+32, c2 = li+64, c3 = li+96;
    int r0 = wv*(NS/2) + hf*RH;

    for (int q = 0; q < 17; q++) {
        int k = 4*q;
        float4 w0v = *(const float4*)(ws + c0*68 + k);
        float4 w1v = *(const float4*)(ws + c1*68 + k);
        float4 w2v = *(const float4*)(ws + c2*68 + k);
        float4 w3v = *(const float4*)(ws + c3*68 + k);
#pragma unroll
        for (int i = 0; i < RH; i++) {
            float4 g = *(const float4*)(gs + (r0+i)*68 + k);
            acc[i][0]=fmaf(g.x,w0v.x,acc[i][0]); acc[i][0]=fmaf(g.y,w0v.y,acc[i][0]);
            acc[i][0]=fmaf(g.z,w0v.z,acc[i][0]); acc[i][0]=fmaf(g.w,w0v.w,acc[i][0]);
            acc[i][1]=fmaf(g.x,w1v.x,acc[i][1]); acc[i][1]=fmaf(g.y,w1v.y,acc[i][1]);
            acc[i][1]=fmaf(g.z,w1v.z,acc[i][1]); acc[i][1]=fmaf(g.w,w1v.w,acc[i][1]);
            acc[i][2]=fmaf(g.x,w2v.x,acc[i][2]); acc[i][2]=fmaf(g.y,w2v.y,acc[i][2]);
            acc[i][2]=fmaf(g.z,w2v.z,acc[i][2]); acc[i][2]=fmaf(g.w,w2v.w,acc[i][2]);
            acc[i][3]=fmaf(g.x,w3v.x,acc[i][3]); acc[i][3]=fmaf(g.y,w3v.y,acc[i][3]);
            acc[i][3]=fmaf(g.z,w3v.z,acc[i][3]); acc[i][3]=fmaf(g.w,w3v.w,acc[i][3]);
        }
    }

    long long gbase = (long long)m0*NS*CO;
    float s[4] = {0,0,0,0}, qv[4] = {0,0,0,0};
#pragma unroll
    for (int i = 0; i < RH; i++) {
        long long rb = gbase + (long long)(r0+i)*CO;
        x1[rb+c0]=acc[i][0]; x1[rb+c1]=acc[i][1];
        x1[rb+c2]=acc[i][2]; x1[rb+c3]=acc[i][3];
#pragma unroll
        for (int j = 0; j < 4; j++) {
            s[j] += acc[i][j]; qv[j] = fmaf(acc[i][j], acc[i][j], qv[j]);
        }
    }
    int p = wv*2 + hf;
    sred[p*128+c0]=s[0]; sred[p*128+c1]=s[1]; sred[p*128+c2]=s[2]; sred[p*128+c3]=s[3];
    qred[p*128+c0]=qv[0]; qred[p*128+c1]=qv[1]; qred[p*128+c2]=qv[2]; qred[p*128+c3]=qv[3];
    __syncthreads();
    if (t < 128) {
        float ss = 0.f, qq = 0.f;
#pragma unroll
        for (int r = 0; r < 8; r++) { ss += sred[r*128+t]; qq += qred[r*128+t]; }
        part[(long long)bx*256 + t]       = ss;
        part[(long long)bx*256 + 128 + t] = qq;
    }
}

// ---------------------------------------------------------------------------
// Pass 2 (MFMA split-bf16, v2): 64 rows/block = GM groups of NS. 4 waves;
// wave owns 32 channels, MT=4 m-tiles. B-fragments hoisted to registers.
// Partial stats -> global rows (no atomics); per-group max/min direct.
// ---------------------------------------------------------------------------
template<int NS, int GM>
__global__ void __launch_bounds__(256, 2) sa_pass2m(
    const float* __restrict__ x1, const ushort* __restrict__ wh,
    const ushort* __restrict__ wl,
    const float* __restrict__ g0, const float* __restrict__ b0,
    const float* __restrict__ s1sum, const float* __restrict__ s1sq,
    float* __restrict__ part,
    float* __restrict__ mxo, float* __restrict__ mno, float invN)
{
    const int TPG = NS/16;             // m-tiles per group
    __shared__ ushort ah[64*136];
    __shared__ ushort al[64*136];
    __shared__ float kv[128], sv[128];
    int bx = blockIdx.x, t = threadIdx.x;
    int m0 = bx * GM;
    int wv = t >> 6, lane = t & 63, l16 = lane & 15, qo = lane >> 4;

    if (t < 128) {
        float mean = s1sum[t] * invN;
        float var  = s1sq[t] * invN - mean * mean;
        float k    = rsqrtf(var + 1e-5f) * g0[t];
        kv[t] = k;
        sv[t] = b0[t] - mean * k;
    }
    __syncthreads();

    long long base = (long long)m0 * NS * 128;   // 64 contiguous rows
    for (int e = t; e < 64*32; e += 256) {
        int n = e >> 5, c4 = e & 31;
        float4 v  = *(const float4*)(x1 + base + (long long)n*128 + 4*c4);
        float4 kk = *(const float4*)(kv + 4*c4);
        float4 ss = *(const float4*)(sv + 4*c4);
        float h0 = fmaxf(fmaf(v.x, kk.x, ss.x), 0.f);
        float h1 = fmaxf(fmaf(v.y, kk.y, ss.y), 0.f);
        float h2 = fmaxf(fmaf(v.z, kk.z, ss.z), 0.f);
        float h3 = fmaxf(fmaf(v.w, kk.w, ss.w), 0.f);
        int o = n*136 + 4*c4;
        ushort u0 = f2b(h0), u1 = f2b(h1), u2 = f2b(h2), u3 = f2b(h3);
        ah[o+0] = u0; ah[o+1] = u1; ah[o+2] = u2; ah[o+3] = u3;
        al[o+0] = f2b(h0 - b2f(u0));
        al[o+1] = f2b(h1 - b2f(u1));
        al[o+2] = f2b(h2 - b2f(u2));
        al[o+3] = f2b(h3 - b2f(u3));
    }

    int n0 = 32*wv;
    short8 bh[4][2], bl[4][2];
#pragma unroll
    for (int ks = 0; ks < 4; ks++) {
#pragma unroll
        for (int nt = 0; nt < 2; nt++) {
            long long wo = (long long)(n0 + 16*nt + l16)*128 + ks*32 + qo*8;
            bh[ks][nt] = *(const short8*)(wh + wo);
            bl[ks][nt] = *(const short8*)(wl + wo);
        }
    }
    __syncthreads();

    floatx4 acc[4][2];
#pragma unroll
    for (int i = 0; i < 4; i++) {
        acc[i][0] = (floatx4){0.f,0.f,0.f,0.f};
        acc[i][1] = (floatx4){0.f,0.f,0.f,0.f};
    }

#pragma unroll
    for (int ks = 0; ks < 4; ks++) {
        int kb = ks*32 + qo*8;
#pragma unroll
        for (int mt = 0; mt < 4; mt++) {
            int ao = (16*mt + l16)*136 + kb;
            short8 fh = *(const short8*)(ah + ao);
            short8 fl = *(const short8*)(al + ao);
#pragma unroll
            for (int nt = 0; nt < 2; nt++) {
                acc[mt][nt] = __builtin_amdgcn_mfma_f32_16x16x32_bf16(
                                  fl, bh[ks][nt], acc[mt][nt], 0, 0, 0);
                acc[mt][nt] = __builtin_amdgcn_mfma_f32_16x16x32_bf16(
                                  fh, bl[ks][nt], acc[mt][nt], 0, 0, 0);
                acc[mt][nt] = __builtin_amdgcn_mfma_f32_16x16x32_bf16(
                                  fh, bh[ks][nt], acc[mt][nt], 0, 0, 0);
            }
        }
    }

    // C-layout: col = lane&15 (channel within n-tile), rows = samples.
    float sum[2] = {0.f, 0.f}, sq[2] = {0.f, 0.f};
    float Mx[GM][2], Mn[GM][2];
#pragma unroll
    for (int g = 0; g < GM; g++) {
        Mx[g][0] = -3.4e38f; Mx[g][1] = -3.4e38f;
        Mn[g][0] =  3.4e38f; Mn[g][1] =  3.4e38f;
    }
#pragma unroll
    for (int mt = 0; mt < 4; mt++) {
        int gg = mt / TPG;
#pragma unroll
        for (int nt = 0; nt < 2; nt++) {
#pragma unroll
            for (int r = 0; r < 4; r++) {
                float a = acc[mt][nt][r];
                sum[nt] += a; sq[nt] = fmaf(a, a, sq[nt]);
                Mx[gg][nt] = fmaxf(Mx[gg][nt], a);
                Mn[gg][nt] = fminf(Mn[gg][nt], a);
            }
        }
    }
#pragma unroll
    for (int nt = 0; nt < 2; nt++) {
        sum[nt] += __shfl_xor(sum[nt], 16); sum[nt] += __shfl_xor(sum[nt], 32);
        sq[nt]  += __shfl_xor(sq[nt],  16); sq[nt]  += __shfl_xor(sq[nt],  32);
#pragma unroll
        for (int g = 0; g < GM; g++) {
            Mx[g][nt] = fmaxf(Mx[g][nt], __shfl_xor(Mx[g][nt], 16));
            Mx[g][nt] = fmaxf(Mx[g][nt], __shfl_xor(Mx[g][nt], 32));
            Mn[g][nt] = fminf(Mn[g][nt], __shfl_xor(Mn[g][nt], 16));
            Mn[g][nt] = fminf(Mn[g][nt], __shfl_xor(Mn[g][nt], 32));
        }
    }
    if (lane < 16) {
#pragma unroll
        for (int nt = 0; nt < 2; nt++) {
            int c = n0 + 16*nt + lane;
            part[(long long)bx*256 + c]       = sum[nt];
            part[(long long)bx*256 + 128 + c] = sq[nt];
#pragma unroll
            for (int g = 0; g < GM; g++) {
                mxo[(long long)(m0+g)*128 + c] = Mx[g][nt];
                mno[(long long)(m0+g)*128 + c] = Mn[g][nt];
            }
        }
    }
}

// ---------------------------------------------------------------------------
// Pass 3 (tiny): out = relu(k2 * (k2>=0 ? max : min) + sh2) per (m, o).
// ---------------------------------------------------------------------------
__global__ void __launch_bounds__(256, 1) sa_pass3(
    const float* __restrict__ mxo, const float* __restrict__ mno,
    const float* __restrict__ g1, const float* __restrict__ b1,
    const float* __restrict__ s2sum, const float* __restrict__ s2sq,
    float* __restrict__ outp, float invN)
{
    int i = blockIdx.x * 256 + threadIdx.x;
    if (i >= MTOT*128) return;
    int m = i >> 7, o = i & 127;
    float mean = s2sum[o] * invN;
    float var  = s2sq[o] * invN - mean * mean;
    float k    = rsqrtf(var + 1e-5f) * g1[o];
    float sh   = b1[o] - mean * k;
    float v    = (k >= 0.f) ? mxo[i] : mno[i];
    float r    = fmaf(v, k, sh);
    outp[(long long)m*256 + o] = r > 0.f ? r : 0.f;
}

// ---------------------------------------------------------------------------
extern "C" void kernel_launch(void* const* d_in, const int* in_sizes, int n_in,
                              void* d_out, int out_size, void* d_ws, size_t ws_size,
                              hipStream_t stream)
{
    const float* xyz  = (const float*)d_in[0];
    const float* feat = (const float*)d_in[1];
    const float* nxyz = (const float*)d_in[2];
    const float* w00 = (const float*)d_in[5];
    const float* g00 = (const float*)d_in[6];
    const float* b00 = (const float*)d_in[7];
    const float* w01 = (const float*)d_in[8];
    const float* g01 = (const float*)d_in[9];
    const float* b01 = (const float*)d_in[10];
    const float* w10 = (const float*)d_in[11];
    const float* g10 = (const float*)d_in[12];
    const float* b10 = (const float*)d_in[13];
    const float* w11 = (const float*)d_in[14];
    const float* g11 = (const float*)d_in[15];
    const float* b11 = (const float*)d_in[16];
    float* out = (float*)d_out;

    char*  wsb    = (char*)d_ws;
    float* stats  = (float*)(wsb);
    int*   idx0   = (int*)(wsb + 4096);
    int*   idx1   = (int*)(wsb + 4096 + 524288);
    int*   empty0 = (int*)(wsb + 4096 + 524288 + 1048576);
    int*   empty1 = (int*)(wsb + 4096 + 524288 + 1048576 + 32768);
    float* x      = (float*)(wsb + 4096 + 524288 + 1048576 + 65536);
    float* mx0    = (float*)(wsb + 150000000);
    float* mn0    = (float*)(wsb + 155000000);
    float* mx1    = (float*)(wsb + 160000000);
    float* mn1    = (float*)(wsb + 165000000);
    ushort* whA   = (ushort*)(wsb + 170000000);
    ushort* wlA   = (ushort*)(wsb + 171000000);
    ushort* whB   = (ushort*)(wsb + 172000000);
    ushort* wlB   = (ushort*)(wsb + 173000000);
    float* part1  = (float*)(wsb + 180000000);   // 4096*256 = 4 MB
    float* part2  = (float*)(wsb + 185000000);   // 4096*256 = 4 MB

    StackSAModuleMSG_85761906966880_kernel<<<96, 256, 0, stream>>>(nxyz, out, stats);
    sa_wprep<<<64, 256, 0, stream>>>(w01, w11, whA, wlA, whB, wlB);
    sa_ballq<<<MTOT, 64, 0, stream>>>(xyz, nxyz, idx0, idx1, empty0, empty1);

    float* fout = out + MTOT*3;
    const float invN0 = 1.0f / (float)(MTOT*16);
    const float invN1 = 1.0f / (float)(MTOT*32);
    const int P3B = (MTOT*128 + 255) / 256;
    const int GB  = MTOT/2;

    // scale 0 (r=0.2, ns=16)
    sa_pass1<16><<<GB, 256, 0, stream>>>(xyz, feat, nxyz, idx0, empty0, w00,
                                         x, part1);
    sa_reduce<<<256, 256, 0, stream>>>(part1, stats + 0, GB);
    sa_pass2m<16,4><<<MTOT/4, 256, 0, stream>>>(x, whA, wlA, g00, b00,
                                                stats + 0, stats + 128,
                                                part2, mx0, mn0, invN0);
    sa_reduce<<<256, 256, 0, stream>>>(part2, stats + 256, MTOT/4);
    sa_pass3<<<P3B, 256, 0, stream>>>(mx0, mn0, g01, b01, stats + 256, stats + 384,
                                      fout, invN0);
    // scale 1 (r=0.4, ns=32)
    sa_pass1<32><<<GB, 256, 0, stream>>>(xyz, feat, nxyz, idx1, empty1, w10,
                                         x, part1);
    sa_reduce<<<256, 256, 0, stream>>>(part1, stats + 512, GB);
    sa_pass2m<32,2><<<MTOT/2, 256, 0, stream>>>(x, whB, wlB, g10, b10,
                                                stats + 512, stats + 640,
                                                part2, mx1, mn1, invN1);
    sa_reduce<<<256, 256, 0, stream>>>(part2, stats + 768, MTOT/2);
    sa_pass3<<<P3B, 256, 0, stream>>>(mx1, mn1, g11, b11, stats + 768, stats + 896,
                                      fout + 128, invN1);

    hipError_t e = hipGetLastError();
    if (e != hipSuccess) EPR("[KL] enqueue err=%d (%s)\n", (int)e, hipGetErrorString(e));
}

// Round 25
// 296.565 us; speedup vs baseline: 2.6450x; 1.2332x over previous
//
#include <hip/hip_runtime.h>
#include <stdio.h>

#define NBP   8192
#define MTOT  8192
#define CIN   64
#define CO    128

#define EPR(...) do { fprintf(stderr, __VA_ARGS__); fflush(stderr); } while (0)

typedef short short8 __attribute__((ext_vector_type(8)));
typedef float floatx4 __attribute__((ext_vector_type(4)));
typedef unsigned short ushort;

__device__ __forceinline__ ushort f2b(float f)
{
    union { unsigned int i; float f; } x; x.f = f;
    return (ushort)((x.i + 0x7fffu + ((x.i >> 16) & 1u)) >> 16);
}
__device__ __forceinline__ float b2f(ushort u)
{
    union { unsigned int i; float f; } x; x.i = ((unsigned int)u) << 16;
    return x.f;
}

// ---------------------------------------------------------------------------
// Zero stats; write output 0 = new_xyz (f32 copy).
// ---------------------------------------------------------------------------
__global__ void __launch_bounds__(256, 1) StackSAModuleMSG_85761906966880_kernel(
    const float* __restrict__ nxyz, float* __restrict__ out, float* __restrict__ stats)
{
    int i = blockIdx.x * 256 + threadIdx.x;
    if (i < 1024) stats[i] = 0.f;
    if (i < MTOT*3) out[i] = nxyz[i];
}

// ---------------------------------------------------------------------------
// Split weights into bf16 hi/lo. W1 (128x128) linear; W0 (128x67) permuted
// to [channel][96]: kd<64 -> c=kd+3 (feat), kd in 64..66 -> c=kd-64 (dxyz),
// kd>=67 -> 0 pad. Matches the gather's permuted k-layout.
// ---------------------------------------------------------------------------
__global__ void __launch_bounds__(256, 1) sa_wprep(
    const float* __restrict__ w00, const float* __restrict__ w01,
    const float* __restrict__ w10, const float* __restrict__ w11,
    ushort* __restrict__ wh00, ushort* __restrict__ wl00,
    ushort* __restrict__ wh01, ushort* __restrict__ wl01,
    ushort* __restrict__ wh10, ushort* __restrict__ wl10,
    ushort* __restrict__ wh11, ushort* __restrict__ wl11)
{
    int i = blockIdx.x * 256 + threadIdx.x;
    if (i < 128*128) {
        float a = w01[i];
        ushort h = f2b(a);
        wh01[i] = h; wl01[i] = f2b(a - b2f(h));
        float b = w11[i];
        ushort h2 = f2b(b);
        wh11[i] = h2; wl11[i] = f2b(b - b2f(h2));
    }
    if (i < 128*96) {
        int o = i / 96, kd = i - o*96;
        int c = (kd < 64) ? (kd + 3) : ((kd < 67) ? (kd - 64) : -1);
        float a = (c >= 0) ? w00[o*67 + c] : 0.f;
        ushort h = f2b(a);
        wh00[i] = h; wl00[i] = f2b(a - b2f(h));
        float b = (c >= 0) ? w10[o*67 + c] : 0.f;
        ushort h2 = f2b(b);
        wh10[i] = h2; wl10[i] = f2b(b - b2f(h2));
    }
}

// ---------------------------------------------------------------------------
// Reduce per-block partial stats rows (256 floats each) into stats dst.
// ---------------------------------------------------------------------------
__global__ void __launch_bounds__(256, 1) sa_reduce(
    const float* __restrict__ part, float* __restrict__ dst, int nb)
{
    __shared__ float red[256];
    int b = blockIdx.x, t = threadIdx.x;
    float s = 0.f;
    for (int i = t; i < nb; i += 256) s += part[(long long)i*256 + b];
    red[t] = s;
    __syncthreads();
    for (int off = 128; off > 0; off >>= 1) {
        if (t < off) red[t] += red[t + off];
        __syncthreads();
    }
    if (t == 0) dst[b] = red[0];
}

// ---------------------------------------------------------------------------
// Ball query, both scales: one wave per query; f64 d2 (matches np gold).
// ---------------------------------------------------------------------------
__global__ void __launch_bounds__(64, 1) sa_ballq(
    const float* __restrict__ xyz, const float* __restrict__ new_xyz,
    int* __restrict__ idx0, int* __restrict__ idx1,
    int* __restrict__ empty0, int* __restrict__ empty1)
{
    const double r2a = 0.2 * 0.2;
    const double r2b = 0.4 * 0.4;
    int m    = blockIdx.x;
    int lane = threadIdx.x;
    int b    = m >> 11;
    int base = b * NBP;

    double nx = (double)new_xyz[3*m+0];
    double ny = (double)new_xyz[3*m+1];
    double nz = (double)new_xyz[3*m+2];
    double nn = nx*nx + ny*ny + nz*nz;

    int cnt0 = 0, cnt1 = 0;
    int first0 = base, first1 = base;
    unsigned long long lt = (1ull << lane) - 1ull;

    for (int j = 0; j < NBP; j += 64) {
        int gi = base + j + lane;
        double px = (double)xyz[3*gi+0];
        double py = (double)xyz[3*gi+1];
        double pz = (double)xyz[3*gi+2];
        double pp = px*px + py*py + pz*pz;
        double dt = nx*px + ny*py + nz*pz;
        double d2 = nn + pp - 2.0*dt;
        bool in0 = d2 < r2a;
        bool in1 = d2 < r2b;
        unsigned long long m0 = __ballot(in0);
        unsigned long long m1 = __ballot(in1);
        if (in0) {
            int p = cnt0 + __popcll(m0 & lt);
            if (p < 16) idx0[m*16 + p] = gi;
        }
        if (in1) {
            int p = cnt1 + __popcll(m1 & lt);
            if (p < 32) idx1[m*32 + p] = gi;
        }
        if (cnt0 == 0 && m0) first0 = base + j + (__ffsll((long long)m0) - 1);
        if (cnt1 == 0 && m1) first1 = base + j + (__ffsll((long long)m1) - 1);
        cnt0 += __popcll(m0);
        cnt1 += __popcll(m1);
        if (cnt0 >= 16 && cnt1 >= 32) break;
    }
    int c0 = cnt0 < 16 ? cnt0 : 16;
    int c1 = cnt1 < 32 ? cnt1 : 32;
    if (lane >= c0 && lane < 16) idx0[m*16 + lane] = first0;
    if (lane >= c1 && lane < 32) idx1[m*32 + lane] = first1;
    if (lane == 0) { empty0[m] = (cnt0 == 0); empty1[m] = (cnt1 == 0); }
}

// ---------------------------------------------------------------------------
// Shared gather: 64 rows of G into bf16 hi/lo LDS panels (stride 136),
// permuted k-layout: feat 0..63 | dxyz 64..66 | zeros 67..95.
// ---------------------------------------------------------------------------
template<int NS, int GM>
__device__ __forceinline__ void gather_G(
    const float* __restrict__ xyz, const float* __restrict__ feat,
    const float* __restrict__ nxyz, const int* __restrict__ idx,
    const int* __restrict__ empty, int m0, int t,
    ushort* ah, ushort* al, int* lidx)
{
    if (t < 64) lidx[t] = idx[(long long)m0*NS + t];
    __syncthreads();
    int emp[GM];
#pragma unroll
    for (int g = 0; g < GM; g++) emp[g] = empty[m0 + g];

    for (int e = t; e < 64*16; e += 256) {          // feat -> k 0..63
        int n = e >> 4, c4 = e & 15;
        int g = n / NS;
        int gi = lidx[n];
        float4 v = *(const float4*)(feat + (long long)gi*CIN + 4*c4);
        if (emp[g]) { v.x = 0.f; v.y = 0.f; v.z = 0.f; v.w = 0.f; }
        float vv[4] = {v.x, v.y, v.z, v.w};
        int o = n*136 + 4*c4;
#pragma unroll
        for (int u = 0; u < 4; u++) {
            ushort h = f2b(vv[u]);
            ah[o+u] = h; al[o+u] = f2b(vv[u] - b2f(h));
        }
    }
    for (int e = t; e < 64*29; e += 256) {          // zeros k 67..95
        int n = e / 29, c = e - n*29;
        ah[n*136 + 67 + c] = 0; al[n*136 + 67 + c] = 0;
    }
    for (int e = t; e < 64*4; e += 256) {           // dxyz k 64..66
        int n = e >> 2, c = e & 3;
        if (c < 3) {
            int g = n / NS;
            float v = 0.f;
            if (!emp[g]) {
                int gi = lidx[n];
                v = xyz[3*gi+c] - nxyz[3*(m0+g)+c];
            }
            ushort h = f2b(v);
            ah[n*136 + 64 + c] = h; al[n*136 + 64 + c] = f2b(v - b2f(h));
        }
    }
    __syncthreads();
}

// ---------------------------------------------------------------------------
// Kernel A: gather + MFMA GEMM1 (split-bf16, K=96) -> layer-1 partial stats.
// No x1 materialization.
// ---------------------------------------------------------------------------
template<int NS, int GM>
__global__ void __launch_bounds__(256, 2) sa_stats1(
    const float* __restrict__ xyz, const float* __restrict__ feat,
    const float* __restrict__ nxyz, const int* __restrict__ idx,
    const int* __restrict__ empty,
    const ushort* __restrict__ wh0, const ushort* __restrict__ wl0,
    float* __restrict__ part)
{
    __shared__ ushort ah[64*136];
    __shared__ ushort al[64*136];
    __shared__ int lidx[64];
    int bx = blockIdx.x, t = threadIdx.x;
    int m0 = bx * GM;
    int wv = t >> 6, lane = t & 63, l16 = lane & 15, qo = lane >> 4;

    gather_G<NS, GM>(xyz, feat, nxyz, idx, empty, m0, t, ah, al, lidx);

    int n0 = 32*wv;
    short8 bh[3][2], bl[3][2];
#pragma unroll
    for (int ks = 0; ks < 3; ks++)
#pragma unroll
        for (int nt = 0; nt < 2; nt++) {
            long long wo = (long long)(n0 + 16*nt + l16)*96 + ks*32 + qo*8;
            bh[ks][nt] = *(const short8*)(wh0 + wo);
            bl[ks][nt] = *(const short8*)(wl0 + wo);
        }

    floatx4 acc[4][2];
#pragma unroll
    for (int i = 0; i < 4; i++) {
        acc[i][0] = (floatx4){0.f,0.f,0.f,0.f};
        acc[i][1] = (floatx4){0.f,0.f,0.f,0.f};
    }
#pragma unroll
    for (int ks = 0; ks < 3; ks++) {
        int kb = ks*32 + qo*8;
#pragma unroll
        for (int mt = 0; mt < 4; mt++) {
            int ao = (16*mt + l16)*136 + kb;
            short8 fh = *(const short8*)(ah + ao);
            short8 fl = *(const short8*)(al + ao);
#pragma unroll
            for (int nt = 0; nt < 2; nt++) {
                acc[mt][nt] = __builtin_amdgcn_mfma_f32_16x16x32_bf16(
                                  fl, bh[ks][nt], acc[mt][nt], 0, 0, 0);
                acc[mt][nt] = __builtin_amdgcn_mfma_f32_16x16x32_bf16(
                                  fh, bl[ks][nt], acc[mt][nt], 0, 0, 0);
                acc[mt][nt] = __builtin_amdgcn_mfma_f32_16x16x32_bf16(
                                  fh, bh[ks][nt], acc[mt][nt], 0, 0, 0);
            }
        }
    }

    float sum[2] = {0.f,0.f}, sq[2] = {0.f,0.f};
#pragma unroll
    for (int mt = 0; mt < 4; mt++)
#pragma unroll
        for (int nt = 0; nt < 2; nt++)
#pragma unroll
            for (int r = 0; r < 4; r++) {
                float a = acc[mt][nt][r];
                sum[nt] += a; sq[nt] = fmaf(a, a, sq[nt]);
            }
#pragma unroll
    for (int nt = 0; nt < 2; nt++) {
        sum[nt] += __shfl_xor(sum[nt], 16); sum[nt] += __shfl_xor(sum[nt], 32);
        sq[nt]  += __shfl_xor(sq[nt],  16); sq[nt]  += __shfl_xor(sq[nt],  32);
    }
    if (lane < 16) {
#pragma unroll
        for (int nt = 0; nt < 2; nt++) {
            int c = n0 + 16*nt + lane;
            part[(long long)bx*256 + c]       = sum[nt];
            part[(long long)bx*256 + 128 + c] = sq[nt];
        }
    }
}

// ---------------------------------------------------------------------------
// Kernel B (fused): gather + MFMA GEMM1 -> BN1+ReLU in registers -> h into
// the same LDS panels -> MFMA GEMM2 -> stats2 partials + per-group max/min.
// ---------------------------------------------------------------------------
template<int NS, int GM>
__global__ void __launch_bounds__(256, 2) sa_fused(
    const float* __restrict__ xyz, const float* __restrict__ feat,
    const float* __restrict__ nxyz, const int* __restrict__ idx,
    const int* __restrict__ empty,
    const ushort* __restrict__ wh0, const ushort* __restrict__ wl0,
    const ushort* __restrict__ wh1, const ushort* __restrict__ wl1,
    const float* __restrict__ g0, const float* __restrict__ b0,
    const float* __restrict__ s1sum, const float* __restrict__ s1sq,
    float* __restrict__ part,
    float* __restrict__ mxo, float* __restrict__ mno, float invN)
{
    const int TPG = NS/16;
    __shared__ ushort ah[64*136];
    __shared__ ushort al[64*136];
    __shared__ float kv[128], sv[128];
    __shared__ int lidx[64];
    int bx = blockIdx.x, t = threadIdx.x;
    int m0 = bx * GM;
    int wv = t >> 6, lane = t & 63, l16 = lane & 15, qo = lane >> 4;

    if (t < 128) {
        float mean = s1sum[t] * invN;
        float var  = s1sq[t] * invN - mean * mean;
        float k    = rsqrtf(var + 1e-5f) * g0[t];
        kv[t] = k;
        sv[t] = b0[t] - mean * k;
    }
    gather_G<NS, GM>(xyz, feat, nxyz, idx, empty, m0, t, ah, al, lidx);

    int n0 = 32*wv;
    {   // ---- GEMM1 ----
        short8 bh[3][2], bl[3][2];
#pragma unroll
        for (int ks = 0; ks < 3; ks++)
#pragma unroll
            for (int nt = 0; nt < 2; nt++) {
                long long wo = (long long)(n0 + 16*nt + l16)*96 + ks*32 + qo*8;
                bh[ks][nt] = *(const short8*)(wh0 + wo);
                bl[ks][nt] = *(const short8*)(wl0 + wo);
            }
        floatx4 acc[4][2];
#pragma unroll
        for (int i = 0; i < 4; i++) {
            acc[i][0] = (floatx4){0.f,0.f,0.f,0.f};
            acc[i][1] = (floatx4){0.f,0.f,0.f,0.f};
        }
#pragma unroll
        for (int ks = 0; ks < 3; ks++) {
            int kb = ks*32 + qo*8;
#pragma unroll
            for (int mt = 0; mt < 4; mt++) {
                int ao = (16*mt + l16)*136 + kb;
                short8 fh = *(const short8*)(ah + ao);
                short8 fl = *(const short8*)(al + ao);
#pragma unroll
                for (int nt = 0; nt < 2; nt++) {
                    acc[mt][nt] = __builtin_amdgcn_mfma_f32_16x16x32_bf16(
                                      fl, bh[ks][nt], acc[mt][nt], 0, 0, 0);
                    acc[mt][nt] = __builtin_amdgcn_mfma_f32_16x16x32_bf16(
                                      fh, bl[ks][nt], acc[mt][nt], 0, 0, 0);
                    acc[mt][nt] = __builtin_amdgcn_mfma_f32_16x16x32_bf16(
                                      fh, bh[ks][nt], acc[mt][nt], 0, 0, 0);
                }
            }
        }
        __syncthreads();   // all G reads done; panels can be overwritten
        // BN1 + ReLU in registers (C-layout: col=lane&15=channel, row=sample)
#pragma unroll
        for (int nt = 0; nt < 2; nt++) {
            int c = n0 + 16*nt + l16;
            float k = kv[c], s = sv[c];
#pragma unroll
            for (int mt = 0; mt < 4; mt++) {
#pragma unroll
                for (int r = 0; r < 4; r++) {
                    float h = fmaxf(fmaf(acc[mt][nt][r], k, s), 0.f);
                    int row = 16*mt + qo*4 + r;
                    ushort hi = f2b(h);
                    ah[row*136 + c] = hi;
                    al[row*136 + c] = f2b(h - b2f(hi));
                }
            }
        }
    }
    __syncthreads();       // h panels complete

    // ---- GEMM2 ----
    short8 bh[4][2], bl[4][2];
#pragma unroll
    for (int ks = 0; ks < 4; ks++)
#pragma unroll
        for (int nt = 0; nt < 2; nt++) {
            long long wo = (long long)(n0 + 16*nt + l16)*128 + ks*32 + qo*8;
            bh[ks][nt] = *(const short8*)(wh1 + wo);
            bl[ks][nt] = *(const short8*)(wl1 + wo);
        }
    floatx4 acc[4][2];
#pragma unroll
    for (int i = 0; i < 4; i++) {
        acc[i][0] = (floatx4){0.f,0.f,0.f,0.f};
        acc[i][1] = (floatx4){0.f,0.f,0.f,0.f};
    }
#pragma unroll
    for (int ks = 0; ks < 4; ks++) {
        int kb = ks*32 + qo*8;
#pragma unroll
        for (int mt = 0; mt < 4; mt++) {
            int ao = (16*mt + l16)*136 + kb;
            short8 fh = *(const short8*)(ah + ao);
            short8 fl = *(const short8*)(al + ao);
#pragma unroll
            for (int nt = 0; nt < 2; nt++) {
                acc[mt][nt] = __builtin_amdgcn_mfma_f32_16x16x32_bf16(
                                  fl, bh[ks][nt], acc[mt][nt], 0, 0, 0);
                acc[mt][nt] = __builtin_amdgcn_mfma_f32_16x16x32_bf16(
                                  fh, bl[ks][nt], acc[mt][nt], 0, 0, 0);
                acc[mt][nt] = __builtin_amdgcn_mfma_f32_16x16x32_bf16(
                                  fh, bh[ks][nt], acc[mt][nt], 0, 0, 0);
            }
        }
    }

    float sum[2] = {0.f,0.f}, sq[2] = {0.f,0.f};
    float Mx[GM][2], Mn[GM][2];
#pragma unroll
    for (int g = 0; g < GM; g++) {
        Mx[g][0] = -3.4e38f; Mx[g][1] = -3.4e38f;
        Mn[g][0] =  3.4e38f; Mn[g][1] =  3.4e38f;
    }
#pragma unroll
    for (int mt = 0; mt < 4; mt++) {
        int gg = mt / TPG;
#pragma unroll
        for (int nt = 0; nt < 2; nt++)
#pragma unroll
            for (int r = 0; r < 4; r++) {
                float a = acc[mt][nt][r];
                sum[nt] += a; sq[nt] = fmaf(a, a, sq[nt]);
                Mx[gg][nt] = fmaxf(Mx[gg][nt], a);
                Mn[gg][nt] = fminf(Mn[gg][nt], a);
            }
    }
#pragma unroll
    for (int nt = 0; nt < 2; nt++) {
        sum[nt] += __shfl_xor(sum[nt], 16); sum[nt] += __shfl_xor(sum[nt], 32);
        sq[nt]  += __shfl_xor(sq[nt],  16); sq[nt]  += __shfl_xor(sq[nt],  32);
#pragma unroll
        for (int g = 0; g < GM; g++) {
            Mx[g][nt] = fmaxf(Mx[g][nt], __shfl_xor(Mx[g][nt], 16));
            Mx[g][nt] = fmaxf(Mx[g][nt], __shfl_xor(Mx[g][nt], 32));
            Mn[g][nt] = fminf(Mn[g][nt], __shfl_xor(Mn[g][nt], 16));
            Mn[g][nt] = fminf(Mn[g][nt], __shfl_xor(Mn[g][nt], 32));
        }
    }
    if (lane < 16) {
#pragma unroll
        for (int nt = 0; nt < 2; nt++) {
            int c = n0 + 16*nt + lane;
            part[(long long)bx*256 + c]       = sum[nt];
            part[(long long)bx*256 + 128 + c] = sq[nt];
#pragma unroll
            for (int g = 0; g < GM; g++) {
                mxo[(long long)(m0+g)*128 + c] = Mx[g][nt];
                mno[(long long)(m0+g)*128 + c] = Mn[g][nt];
            }
        }
    }
}

// ---------------------------------------------------------------------------
// Pass 3 (tiny): out = relu(k2 * (k2>=0 ? max : min) + sh2) per (m, o).
// ---------------------------------------------------------------------------
__global__ void __launch_bounds__(256, 1) sa_pass3(
    const float* __restrict__ mxo, const float* __restrict__ mno,
    const float* __restrict__ g1, const float* __restrict__ b1,
    const float* __restrict__ s2sum, const float* __restrict__ s2sq,
    float* __restrict__ outp, float invN)
{
    int i = blockIdx.x * 256 + threadIdx.x;
    if (i >= MTOT*128) return;
    int m = i >> 7, o = i & 127;
    float mean = s2sum[o] * invN;
    float var  = s2sq[o] * invN - mean * mean;
    float k    = rsqrtf(var + 1e-5f) * g1[o];
    float sh   = b1[o] - mean * k;
    float v    = (k >= 0.f) ? mxo[i] : mno[i];
    float r    = fmaf(v, k, sh);
    outp[(long long)m*256 + o] = r > 0.f ? r : 0.f;
}

// ---------------------------------------------------------------------------
extern "C" void kernel_launch(void* const* d_in, const int* in_sizes, int n_in,
                              void* d_out, int out_size, void* d_ws, size_t ws_size,
                              hipStream_t stream)
{
    const float* xyz  = (const float*)d_in[0];
    const float* feat = (const float*)d_in[1];
    const float* nxyz = (const float*)d_in[2];
    const float* w00 = (const float*)d_in[5];
    const float* g00 = (const float*)d_in[6];
    const float* b00 = (const float*)d_in[7];
    const float* w01 = (const float*)d_in[8];
    const float* g01 = (const float*)d_in[9];
    const float* b01 = (const float*)d_in[10];
    const float* w10 = (const float*)d_in[11];
    const float* g10 = (const float*)d_in[12];
    const float* b10 = (const float*)d_in[13];
    const float* w11 = (const float*)d_in[14];
    const float* g11 = (const float*)d_in[15];
    const float* b11 = (const float*)d_in[16];
    float* out = (float*)d_out;

    char*  wsb    = (char*)d_ws;
    float* stats  = (float*)(wsb);
    int*   idx0   = (int*)(wsb + 4096);
    int*   idx1   = (int*)(wsb + 4096 + 524288);
    int*   empty0 = (int*)(wsb + 4096 + 524288 + 1048576);
    int*   empty1 = (int*)(wsb + 4096 + 524288 + 1048576 + 32768);
    float* mx0    = (float*)(wsb + 150000000);
    float* mn0    = (float*)(wsb + 155000000);
    float* mx1    = (float*)(wsb + 160000000);
    float* mn1    = (float*)(wsb + 165000000);
    ushort* wh01  = (ushort*)(wsb + 170000000);   // W1 scale0
    ushort* wl01  = (ushort*)(wsb + 171000000);
    ushort* wh11  = (ushort*)(wsb + 172000000);   // W1 scale1
    ushort* wl11  = (ushort*)(wsb + 173000000);
    ushort* wh00  = (ushort*)(wsb + 174000000);   // W0 scale0 (permuted, 128x96)
    ushort* wl00  = (ushort*)(wsb + 175000000);
    ushort* wh10  = (ushort*)(wsb + 176000000);   // W0 scale1
    ushort* wl10  = (ushort*)(wsb + 177000000);
    float* part1  = (float*)(wsb + 180000000);
    float* part2  = (float*)(wsb + 185000000);

    StackSAModuleMSG_85761906966880_kernel<<<96, 256, 0, stream>>>(nxyz, out, stats);
    sa_wprep<<<64, 256, 0, stream>>>(w00, w01, w10, w11,
                                     wh00, wl00, wh01, wl01,
                                     wh10, wl10, wh11, wl11);
    sa_ballq<<<MTOT, 64, 0, stream>>>(xyz, nxyz, idx0, idx1, empty0, empty1);

    float* fout = out + MTOT*3;
    const float invN0 = 1.0f / (float)(MTOT*16);
    const float invN1 = 1.0f / (float)(MTOT*32);
    const int P3B = (MTOT*128 + 255) / 256;

    // scale 0 (r=0.2, ns=16): GM=4 -> 2048 blocks of 64 rows
    sa_stats1<16,4><<<MTOT/4, 256, 0, stream>>>(xyz, feat, nxyz, idx0, empty0,
                                                wh00, wl00, part1);
    sa_reduce<<<256, 256, 0, stream>>>(part1, stats + 0, MTOT/4);
    sa_fused<16,4><<<MTOT/4, 256, 0, stream>>>(xyz, feat, nxyz, idx0, empty0,
                                               wh00, wl00, wh01, wl01,
                                               g00, b00, stats + 0, stats + 128,
                                               part2, mx0, mn0, invN0);
    sa_reduce<<<256, 256, 0, stream>>>(part2, stats + 256, MTOT/4);
    sa_pass3<<<P3B, 256, 0, stream>>>(mx0, mn0, g01, b01, stats + 256, stats + 384,
                                      fout, invN0);
    // scale 1 (r=0.4, ns=32): GM=2 -> 4096 blocks of 64 rows
    sa_stats1<32,2><<<MTOT/2, 256, 0, stream>>>(xyz, feat, nxyz, idx1, empty1,
                                                wh10, wl10, part1);
    sa_reduce<<<256, 256, 0, stream>>>(part1, stats + 512, MTOT/2);
    sa_fused<32,2><<<MTOT/2, 256, 0, stream>>>(xyz, feat, nxyz, idx1, empty1,
                                               wh10, wl10, wh11, wl11,
                                               g10, b10, stats + 512, stats + 640,
                                               part2, mx1, mn1, invN1);
    sa_reduce<<<256, 256, 0, stream>>>(part2, stats + 768, MTOT/2);
    sa_pass3<<<P3B, 256, 0, stream>>>(mx1, mn1, g11, b11, stats + 768, stats + 896,
                                      fout + 128, invN1);

    hipError_t e = hipGetLastError();
    if (e != hipSuccess) EPR("[KL] enqueue err=%d (%s)\n", (int)e, hipGetErrorString(e));
}

// Round 26
// 285.156 us; speedup vs baseline: 2.7508x; 1.0400x over previous
//
#include <hip/hip_runtime.h>
#include <stdio.h>

#define NBP   8192
#define MTOT  8192
#define CIN   64
#define CO    128

#define EPR(...) do { fprintf(stderr, __VA_ARGS__); fflush(stderr); } while (0)

typedef short short8 __attribute__((ext_vector_type(8)));
typedef float floatx4 __attribute__((ext_vector_type(4)));
typedef unsigned short ushort;

__device__ __forceinline__ ushort f2b(float f)
{
    union { unsigned int i; float f; } x; x.f = f;
    return (ushort)((x.i + 0x7fffu + ((x.i >> 16) & 1u)) >> 16);
}
__device__ __forceinline__ float b2f(ushort u)
{
    union { unsigned int i; float f; } x; x.i = ((unsigned int)u) << 16;
    return x.f;
}

// ---------------------------------------------------------------------------
// Zero stats; write output 0 = new_xyz (f32 copy).
// ---------------------------------------------------------------------------
__global__ void __launch_bounds__(256, 1) StackSAModuleMSG_85761906966880_kernel(
    const float* __restrict__ nxyz, float* __restrict__ out, float* __restrict__ stats)
{
    int i = blockIdx.x * 256 + threadIdx.x;
    if (i < 1024) stats[i] = 0.f;
    if (i < MTOT*3) out[i] = nxyz[i];
}

// ---------------------------------------------------------------------------
// Split weights into bf16 hi/lo. W1 (128x128) linear; W0 (128x67) permuted
// to [channel][96] to match the gather's k-layout.
// ---------------------------------------------------------------------------
__global__ void __launch_bounds__(256, 1) sa_wprep(
    const float* __restrict__ w00, const float* __restrict__ w01,
    const float* __restrict__ w10, const float* __restrict__ w11,
    ushort* __restrict__ wh00, ushort* __restrict__ wl00,
    ushort* __restrict__ wh01, ushort* __restrict__ wl01,
    ushort* __restrict__ wh10, ushort* __restrict__ wl10,
    ushort* __restrict__ wh11, ushort* __restrict__ wl11)
{
    int i = blockIdx.x * 256 + threadIdx.x;
    if (i < 128*128) {
        float a = w01[i];
        ushort h = f2b(a);
        wh01[i] = h; wl01[i] = f2b(a - b2f(h));
        float b = w11[i];
        ushort h2 = f2b(b);
        wh11[i] = h2; wl11[i] = f2b(b - b2f(h2));
    }
    if (i < 128*96) {
        int o = i / 96, kd = i - o*96;
        int c = (kd < 64) ? (kd + 3) : ((kd < 67) ? (kd - 64) : -1);
        float a = (c >= 0) ? w00[o*67 + c] : 0.f;
        ushort h = f2b(a);
        wh00[i] = h; wl00[i] = f2b(a - b2f(h));
        float b = (c >= 0) ? w10[o*67 + c] : 0.f;
        ushort h2 = f2b(b);
        wh10[i] = h2; wl10[i] = f2b(b - b2f(h2));
    }
}

// ---------------------------------------------------------------------------
// Reduce per-block partial stats rows (256 floats each) into stats dst.
// ---------------------------------------------------------------------------
__global__ void __launch_bounds__(256, 1) sa_reduce(
    const float* __restrict__ part, float* __restrict__ dst, int nb)
{
    __shared__ float red[256];
    int b = blockIdx.x, t = threadIdx.x;
    float s = 0.f;
    for (int i = t; i < nb; i += 256) s += part[(long long)i*256 + b];
    red[t] = s;
    __syncthreads();
    for (int off = 128; off > 0; off >>= 1) {
        if (t < off) red[t] += red[t + off];
        __syncthreads();
    }
    if (t == 0) dst[b] = red[0];
}

// ---------------------------------------------------------------------------
// Ball query, both scales: one wave per query; f64 d2 (matches np gold).
// ---------------------------------------------------------------------------
__global__ void __launch_bounds__(64, 1) sa_ballq(
    const float* __restrict__ xyz, const float* __restrict__ new_xyz,
    int* __restrict__ idx0, int* __restrict__ idx1,
    int* __restrict__ empty0, int* __restrict__ empty1)
{
    const double r2a = 0.2 * 0.2;
    const double r2b = 0.4 * 0.4;
    int m    = blockIdx.x;
    int lane = threadIdx.x;
    int b    = m >> 11;
    int base = b * NBP;

    double nx = (double)new_xyz[3*m+0];
    double ny = (double)new_xyz[3*m+1];
    double nz = (double)new_xyz[3*m+2];
    double nn = nx*nx + ny*ny + nz*nz;

    int cnt0 = 0, cnt1 = 0;
    int first0 = base, first1 = base;
    unsigned long long lt = (1ull << lane) - 1ull;

    for (int j = 0; j < NBP; j += 64) {
        int gi = base + j + lane;
        double px = (double)xyz[3*gi+0];
        double py = (double)xyz[3*gi+1];
        double pz = (double)xyz[3*gi+2];
        double pp = px*px + py*py + pz*pz;
        double dt = nx*px + ny*py + nz*pz;
        double d2 = nn + pp - 2.0*dt;
        bool in0 = d2 < r2a;
        bool in1 = d2 < r2b;
        unsigned long long m0 = __ballot(in0);
        unsigned long long m1 = __ballot(in1);
        if (in0) {
            int p = cnt0 + __popcll(m0 & lt);
            if (p < 16) idx0[m*16 + p] = gi;
        }
        if (in1) {
            int p = cnt1 + __popcll(m1 & lt);
            if (p < 32) idx1[m*32 + p] = gi;
        }
        if (cnt0 == 0 && m0) first0 = base + j + (__ffsll((long long)m0) - 1);
        if (cnt1 == 0 && m1) first1 = base + j + (__ffsll((long long)m1) - 1);
        cnt0 += __popcll(m0);
        cnt1 += __popcll(m1);
        if (cnt0 >= 16 && cnt1 >= 32) break;
    }
    int c0 = cnt0 < 16 ? cnt0 : 16;
    int c1 = cnt1 < 32 ? cnt1 : 32;
    if (lane >= c0 && lane < 16) idx0[m*16 + lane] = first0;
    if (lane >= c1 && lane < 32) idx1[m*32 + lane] = first1;
    if (lane == 0) { empty0[m] = (cnt0 == 0); empty1[m] = (cnt1 == 0); }
}

// ---------------------------------------------------------------------------
// Gather 64 rows of G into hi/lo bf16 LDS panels (stride 136).
// ---------------------------------------------------------------------------
template<int NS, int GM>
__device__ __forceinline__ void gather_G(
    const float* __restrict__ xyz, const float* __restrict__ feat,
    const float* __restrict__ nxyz, const int* __restrict__ idx,
    const int* __restrict__ empty, int m0, int t,
    ushort* ah, ushort* al, int* lidx)
{
    if (t < 64) lidx[t] = idx[(long long)m0*NS + t];
    __syncthreads();
    int emp[GM];
#pragma unroll
    for (int g = 0; g < GM; g++) emp[g] = empty[m0 + g];

    for (int e = t; e < 64*16; e += 256) {
        int n = e >> 4, c4 = e & 15;
        int g = n / NS;
        int gi = lidx[n];
        float4 v = *(const float4*)(feat + (long long)gi*CIN + 4*c4);
        if (emp[g]) { v.x = 0.f; v.y = 0.f; v.z = 0.f; v.w = 0.f; }
        float vv[4] = {v.x, v.y, v.z, v.w};
        int o = n*136 + 4*c4;
#pragma unroll
        for (int u = 0; u < 4; u++) {
            ushort h = f2b(vv[u]);
            ah[o+u] = h; al[o+u] = f2b(vv[u] - b2f(h));
        }
    }
    for (int e = t; e < 64*29; e += 256) {
        int n = e / 29, c = e - n*29;
        ah[n*136 + 67 + c] = 0; al[n*136 + 67 + c] = 0;
    }
    for (int e = t; e < 64*4; e += 256) {
        int n = e >> 2, c = e & 3;
        if (c < 3) {
            int g = n / NS;
            float v = 0.f;
            if (!emp[g]) {
                int gi = lidx[n];
                v = xyz[3*gi+c] - nxyz[3*(m0+g)+c];
            }
            ushort h = f2b(v);
            ah[n*136 + 64 + c] = h; al[n*136 + 64 + c] = f2b(v - b2f(h));
        }
    }
    __syncthreads();
}

// ---------------------------------------------------------------------------
// Gather, hi-only variant (for stats: plain bf16, no lo panel).
// ---------------------------------------------------------------------------
template<int NS, int GM>
__device__ __forceinline__ void gather_G_hi(
    const float* __restrict__ xyz, const float* __restrict__ feat,
    const float* __restrict__ nxyz, const int* __restrict__ idx,
    const int* __restrict__ empty, int m0, int t,
    ushort* ah, int* lidx)
{
    if (t < 64) lidx[t] = idx[(long long)m0*NS + t];
    __syncthreads();
    int emp[GM];
#pragma unroll
    for (int g = 0; g < GM; g++) emp[g] = empty[m0 + g];

    for (int e = t; e < 64*16; e += 256) {
        int n = e >> 4, c4 = e & 15;
        int g = n / NS;
        int gi = lidx[n];
        float4 v = *(const float4*)(feat + (long long)gi*CIN + 4*c4);
        if (emp[g]) { v.x = 0.f; v.y = 0.f; v.z = 0.f; v.w = 0.f; }
        int o = n*136 + 4*c4;
        ah[o+0] = f2b(v.x); ah[o+1] = f2b(v.y);
        ah[o+2] = f2b(v.z); ah[o+3] = f2b(v.w);
    }
    for (int e = t; e < 64*29; e += 256) {
        int n = e / 29, c = e - n*29;
        ah[n*136 + 67 + c] = 0;
    }
    for (int e = t; e < 64*4; e += 256) {
        int n = e >> 2, c = e & 3;
        if (c < 3) {
            int g = n / NS;
            float v = 0.f;
            if (!emp[g]) {
                int gi = lidx[n];
                v = xyz[3*gi+c] - nxyz[3*(m0+g)+c];
            }
            ah[n*136 + 64 + c] = f2b(v);
        }
    }
    __syncthreads();
}

// ---------------------------------------------------------------------------
// Kernel A: gather + PLAIN bf16 MFMA GEMM1 (K=96) -> layer-1 partial stats.
// Stats need only ~1e-3 relative accuracy; bf16-RNE is unbiased, so plain
// bf16 suffices (1 MFMA instead of 3, hi-only panels). No x1 store.
// ---------------------------------------------------------------------------
template<int NS, int GM>
__global__ void __launch_bounds__(256, 3) sa_stats1(
    const float* __restrict__ xyz, const float* __restrict__ feat,
    const float* __restrict__ nxyz, const int* __restrict__ idx,
    const int* __restrict__ empty,
    const ushort* __restrict__ wh0,
    float* __restrict__ part)
{
    __shared__ ushort ah[64*136];
    __shared__ int lidx[64];
    int bx = blockIdx.x, t = threadIdx.x;
    int m0 = bx * GM;
    int wv = t >> 6, lane = t & 63, l16 = lane & 15, qo = lane >> 4;

    gather_G_hi<NS, GM>(xyz, feat, nxyz, idx, empty, m0, t, ah, lidx);

    int n0 = 32*wv;
    short8 bh[3][2];
#pragma unroll
    for (int ks = 0; ks < 3; ks++)
#pragma unroll
        for (int nt = 0; nt < 2; nt++) {
            long long wo = (long long)(n0 + 16*nt + l16)*96 + ks*32 + qo*8;
            bh[ks][nt] = *(const short8*)(wh0 + wo);
        }

    floatx4 acc[4][2];
#pragma unroll
    for (int i = 0; i < 4; i++) {
        acc[i][0] = (floatx4){0.f,0.f,0.f,0.f};
        acc[i][1] = (floatx4){0.f,0.f,0.f,0.f};
    }
#pragma unroll
    for (int ks = 0; ks < 3; ks++) {
        int kb = ks*32 + qo*8;
#pragma unroll
        for (int mt = 0; mt < 4; mt++) {
            int ao = (16*mt + l16)*136 + kb;
            short8 fh = *(const short8*)(ah + ao);
#pragma unroll
            for (int nt = 0; nt < 2; nt++)
                acc[mt][nt] = __builtin_amdgcn_mfma_f32_16x16x32_bf16(
                                  fh, bh[ks][nt], acc[mt][nt], 0, 0, 0);
        }
    }

    float sum[2] = {0.f,0.f}, sq[2] = {0.f,0.f};
#pragma unroll
    for (int mt = 0; mt < 4; mt++)
#pragma unroll
        for (int nt = 0; nt < 2; nt++)
#pragma unroll
            for (int r = 0; r < 4; r++) {
                float a = acc[mt][nt][r];
                sum[nt] += a; sq[nt] = fmaf(a, a, sq[nt]);
            }
#pragma unroll
    for (int nt = 0; nt < 2; nt++) {
        sum[nt] += __shfl_xor(sum[nt], 16); sum[nt] += __shfl_xor(sum[nt], 32);
        sq[nt]  += __shfl_xor(sq[nt],  16); sq[nt]  += __shfl_xor(sq[nt],  32);
    }
    if (lane < 16) {
#pragma unroll
        for (int nt = 0; nt < 2; nt++) {
            int c = n0 + 16*nt + lane;
            part[(long long)bx*256 + c]       = sum[nt];
            part[(long long)bx*256 + 128 + c] = sq[nt];
        }
    }
}

// ---------------------------------------------------------------------------
// Kernel B (fused): gather + split-bf16 MFMA GEMM1 -> BN1+ReLU in registers
// -> h into same LDS panels -> split-bf16 MFMA GEMM2 -> stats2 + max/min.
// ---------------------------------------------------------------------------
template<int NS, int GM>
__global__ void __launch_bounds__(256, 2) sa_fused(
    const float* __restrict__ xyz, const float* __restrict__ feat,
    const float* __restrict__ nxyz, const int* __restrict__ idx,
    const int* __restrict__ empty,
    const ushort* __restrict__ wh0, const ushort* __restrict__ wl0,
    const ushort* __restrict__ wh1, const ushort* __restrict__ wl1,
    const float* __restrict__ g0, const float* __restrict__ b0,
    const float* __restrict__ s1sum, const float* __restrict__ s1sq,
    float* __restrict__ part,
    float* __restrict__ mxo, float* __restrict__ mno, float invN)
{
    const int TPG = NS/16;
    __shared__ ushort ah[64*136];
    __shared__ ushort al[64*136];
    __shared__ float kv[128], sv[128];
    __shared__ int lidx[64];
    int bx = blockIdx.x, t = threadIdx.x;
    int m0 = bx * GM;
    int wv = t >> 6, lane = t & 63, l16 = lane & 15, qo = lane >> 4;

    if (t < 128) {
        float mean = s1sum[t] * invN;
        float var  = s1sq[t] * invN - mean * mean;
        float k    = rsqrtf(var + 1e-5f) * g0[t];
        kv[t] = k;
        sv[t] = b0[t] - mean * k;
    }
    gather_G<NS, GM>(xyz, feat, nxyz, idx, empty, m0, t, ah, al, lidx);

    int n0 = 32*wv;
    {   // ---- GEMM1 (split) ----
        short8 bh[3][2], bl[3][2];
#pragma unroll
        for (int ks = 0; ks < 3; ks++)
#pragma unroll
            for (int nt = 0; nt < 2; nt++) {
                long long wo = (long long)(n0 + 16*nt + l16)*96 + ks*32 + qo*8;
                bh[ks][nt] = *(const short8*)(wh0 + wo);
                bl[ks][nt] = *(const short8*)(wl0 + wo);
            }
        floatx4 acc[4][2];
#pragma unroll
        for (int i = 0; i < 4; i++) {
            acc[i][0] = (floatx4){0.f,0.f,0.f,0.f};
            acc[i][1] = (floatx4){0.f,0.f,0.f,0.f};
        }
#pragma unroll
        for (int ks = 0; ks < 3; ks++) {
            int kb = ks*32 + qo*8;
#pragma unroll
            for (int mt = 0; mt < 4; mt++) {
                int ao = (16*mt + l16)*136 + kb;
                short8 fh = *(const short8*)(ah + ao);
                short8 fl = *(const short8*)(al + ao);
#pragma unroll
                for (int nt = 0; nt < 2; nt++) {
                    acc[mt][nt] = __builtin_amdgcn_mfma_f32_16x16x32_bf16(
                                      fl, bh[ks][nt], acc[mt][nt], 0, 0, 0);
                    acc[mt][nt] = __builtin_amdgcn_mfma_f32_16x16x32_bf16(
                                      fh, bl[ks][nt], acc[mt][nt], 0, 0, 0);
                    acc[mt][nt] = __builtin_amdgcn_mfma_f32_16x16x32_bf16(
                                      fh, bh[ks][nt], acc[mt][nt], 0, 0, 0);
                }
            }
        }
        __syncthreads();
#pragma unroll
        for (int nt = 0; nt < 2; nt++) {
            int c = n0 + 16*nt + l16;
            float k = kv[c], s = sv[c];
#pragma unroll
            for (int mt = 0; mt < 4; mt++) {
#pragma unroll
                for (int r = 0; r < 4; r++) {
                    float h = fmaxf(fmaf(acc[mt][nt][r], k, s), 0.f);
                    int row = 16*mt + qo*4 + r;
                    ushort hi = f2b(h);
                    ah[row*136 + c] = hi;
                    al[row*136 + c] = f2b(h - b2f(hi));
                }
            }
        }
    }
    __syncthreads();

    // ---- GEMM2 (split) ----
    short8 bh[4][2], bl[4][2];
#pragma unroll
    for (int ks = 0; ks < 4; ks++)
#pragma unroll
        for (int nt = 0; nt < 2; nt++) {
            long long wo = (long long)(n0 + 16*nt + l16)*128 + ks*32 + qo*8;
            bh[ks][nt] = *(const short8*)(wh1 + wo);
            bl[ks][nt] = *(const short8*)(wl1 + wo);
        }
    floatx4 acc[4][2];
#pragma unroll
    for (int i = 0; i < 4; i++) {
        acc[i][0] = (floatx4){0.f,0.f,0.f,0.f};
        acc[i][1] = (floatx4){0.f,0.f,0.f,0.f};
    }
#pragma unroll
    for (int ks = 0; ks < 4; ks++) {
        int kb = ks*32 + qo*8;
#pragma unroll
        for (int mt = 0; mt < 4; mt++) {
            int ao = (16*mt + l16)*136 + kb;
            short8 fh = *(const short8*)(ah + ao);
            short8 fl = *(const short8*)(al + ao);
#pragma unroll
            for (int nt = 0; nt < 2; nt++) {
                acc[mt][nt] = __builtin_amdgcn_mfma_f32_16x16x32_bf16(
                                  fl, bh[ks][nt], acc[mt][nt], 0, 0, 0);
                acc[mt][nt] = __builtin_amdgcn_mfma_f32_16x16x32_bf16(
                                  fh, bl[ks][nt], acc[mt][nt], 0, 0, 0);
                acc[mt][nt] = __builtin_amdgcn_mfma_f32_16x16x32_bf16(
                                  fh, bh[ks][nt], acc[mt][nt], 0, 0, 0);
            }
        }
    }

    float sum[2] = {0.f,0.f}, sq[2] = {0.f,0.f};
    float Mx[GM][2], Mn[GM][2];
#pragma unroll
    for (int g = 0; g < GM; g++) {
        Mx[g][0] = -3.4e38f; Mx[g][1] = -3.4e38f;
        Mn[g][0] =  3.4e38f; Mn[g][1] =  3.4e38f;
    }
#pragma unroll
    for (int mt = 0; mt < 4; mt++) {
        int gg = mt / TPG;
#pragma unroll
        for (int nt = 0; nt < 2; nt++)
#pragma unroll
            for (int r = 0; r < 4; r++) {
                float a = acc[mt][nt][r];
                sum[nt] += a; sq[nt] = fmaf(a, a, sq[nt]);
                Mx[gg][nt] = fmaxf(Mx[gg][nt], a);
                Mn[gg][nt] = fminf(Mn[gg][nt], a);
            }
    }
#pragma unroll
    for (int nt = 0; nt < 2; nt++) {
        sum[nt] += __shfl_xor(sum[nt], 16); sum[nt] += __shfl_xor(sum[nt], 32);
        sq[nt]  += __shfl_xor(sq[nt],  16); sq[nt]  += __shfl_xor(sq[nt],  32);
#pragma unroll
        for (int g = 0; g < GM; g++) {
            Mx[g][nt] = fmaxf(Mx[g][nt], __shfl_xor(Mx[g][nt], 16));
            Mx[g][nt] = fmaxf(Mx[g][nt], __shfl_xor(Mx[g][nt], 32));
            Mn[g][nt] = fminf(Mn[g][nt], __shfl_xor(Mn[g][nt], 16));
            Mn[g][nt] = fminf(Mn[g][nt], __shfl_xor(Mn[g][nt], 32));
        }
    }
    if (lane < 16) {
#pragma unroll
        for (int nt = 0; nt < 2; nt++) {
            int c = n0 + 16*nt + lane;
            part[(long long)bx*256 + c]       = sum[nt];
            part[(long long)bx*256 + 128 + c] = sq[nt];
#pragma unroll
            for (int g = 0; g < GM; g++) {
                mxo[(long long)(m0+g)*128 + c] = Mx[g][nt];
                mno[(long long)(m0+g)*128 + c] = Mn[g][nt];
            }
        }
    }
}

// ---------------------------------------------------------------------------
// Pass 3 (tiny): out = relu(k2 * (k2>=0 ? max : min) + sh2) per (m, o).
// ---------------------------------------------------------------------------
__global__ void __launch_bounds__(256, 1) sa_pass3(
    const float* __restrict__ mxo, const float* __restrict__ mno,
    const float* __restrict__ g1, const float* __restrict__ b1,
    const float* __restrict__ s2sum, const float* __restrict__ s2sq,
    float* __restrict__ outp, float invN)
{
    int i = blockIdx.x * 256 + threadIdx.x;
    if (i >= MTOT*128) return;
    int m = i >> 7, o = i & 127;
    float mean = s2sum[o] * invN;
    float var  = s2sq[o] * invN - mean * mean;
    float k    = rsqrtf(var + 1e-5f) * g1[o];
    float sh   = b1[o] - mean * k;
    float v    = (k >= 0.f) ? mxo[i] : mno[i];
    float r    = fmaf(v, k, sh);
    outp[(long long)m*256 + o] = r > 0.f ? r : 0.f;
}

// ---------------------------------------------------------------------------
extern "C" void kernel_launch(void* const* d_in, const int* in_sizes, int n_in,
                              void* d_out, int out_size, void* d_ws, size_t ws_size,
                              hipStream_t stream)
{
    const float* xyz  = (const float*)d_in[0];
    const float* feat = (const float*)d_in[1];
    const float* nxyz = (const float*)d_in[2];
    const float* w00 = (const float*)d_in[5];
    const float* g00 = (const float*)d_in[6];
    const float* b00 = (const float*)d_in[7];
    const float* w01 = (const float*)d_in[8];
    const float* g01 = (const float*)d_in[9];
    const float* b01 = (const float*)d_in[10];
    const float* w10 = (const float*)d_in[11];
    const float* g10 = (const float*)d_in[12];
    const float* b10 = (const float*)d_in[13];
    const float* w11 = (const float*)d_in[14];
    const float* g11 = (const float*)d_in[15];
    const float* b11 = (const float*)d_in[16];
    float* out = (float*)d_out;

    char*  wsb    = (char*)d_ws;
    float* stats  = (float*)(wsb);
    int*   idx0   = (int*)(wsb + 4096);
    int*   idx1   = (int*)(wsb + 4096 + 524288);
    int*   empty0 = (int*)(wsb + 4096 + 524288 + 1048576);
    int*   empty1 = (int*)(wsb + 4096 + 524288 + 1048576 + 32768);
    float* mx0    = (float*)(wsb + 150000000);
    float* mn0    = (float*)(wsb + 155000000);
    float* mx1    = (float*)(wsb + 160000000);
    float* mn1    = (float*)(wsb + 165000000);
    ushort* wh01  = (ushort*)(wsb + 170000000);
    ushort* wl01  = (ushort*)(wsb + 171000000);
    ushort* wh11  = (ushort*)(wsb + 172000000);
    ushort* wl11  = (ushort*)(wsb + 173000000);
    ushort* wh00  = (ushort*)(wsb + 174000000);
    ushort* wl00  = (ushort*)(wsb + 175000000);
    ushort* wh10  = (ushort*)(wsb + 176000000);
    ushort* wl10  = (ushort*)(wsb + 177000000);
    float* part1  = (float*)(wsb + 180000000);
    float* part2  = (float*)(wsb + 185000000);

    StackSAModuleMSG_85761906966880_kernel<<<96, 256, 0, stream>>>(nxyz, out, stats);
    sa_wprep<<<64, 256, 0, stream>>>(w00, w01, w10, w11,
                                     wh00, wl00, wh01, wl01,
                                     wh10, wl10, wh11, wl11);
    sa_ballq<<<MTOT, 64, 0, stream>>>(xyz, nxyz, idx0, idx1, empty0, empty1);

    float* fout = out + MTOT*3;
    const float invN0 = 1.0f / (float)(MTOT*16);
    const float invN1 = 1.0f / (float)(MTOT*32);
    const int P3B = (MTOT*128 + 255) / 256;

    // scale 0 (r=0.2, ns=16): GM=4 -> 2048 blocks of 64 rows
    sa_stats1<16,4><<<MTOT/4, 256, 0, stream>>>(xyz, feat, nxyz, idx0, empty0,
                                                wh00, part1);
    sa_reduce<<<256, 256, 0, stream>>>(part1, stats + 0, MTOT/4);
    sa_fused<16,4><<<MTOT/4, 256, 0, stream>>>(xyz, feat, nxyz, idx0, empty0,
                                               wh00, wl00, wh01, wl01,
                                               g00, b00, stats + 0, stats + 128,
                                               part2, mx0, mn0, invN0);
    sa_reduce<<<256, 256, 0, stream>>>(part2, stats + 256, MTOT/4);
    sa_pass3<<<P3B, 256, 0, stream>>>(mx0, mn0, g01, b01, stats + 256, stats + 384,
                                      fout, invN0);
    // scale 1 (r=0.4, ns=32): GM=2 -> 4096 blocks of 64 rows
    sa_stats1<32,2><<<MTOT/2, 256, 0, stream>>>(xyz, feat, nxyz, idx1, empty1,
                                                wh10, part1);
    sa_reduce<<<256, 256, 0, stream>>>(part1, stats + 512, MTOT/2);
    sa_fused<32,2><<<MTOT/2, 256, 0, stream>>>(xyz, feat, nxyz, idx1, empty1,
                                               wh10, wl10, wh11, wl11,
                                               g10, b10, stats + 512, stats + 640,
                                               part2, mx1, mn1, invN1);
    sa_reduce<<<256, 256, 0, stream>>>(part2, stats + 768, MTOT/2);
    sa_pass3<<<P3B, 256, 0, stream>>>(mx1, mn1, g11, b11, stats + 768, stats + 896,
                                      fout + 128, invN1);

    hipError_t e = hipGetLastError();
    if (e != hipSuccess) EPR("[KL] enqueue err=%d (%s)\n", (int)e, hipGetErrorString(e));
}